// Round 1
// baseline (45.859 us; speedup 1.0000x reference)
//
#include <hip/hip_runtime.h>

// Problem constants (match reference setup_inputs)
#define MAX_REQS   8192
#define MAX_BLOCKS 4096
#define NBT        (MAX_REQS * MAX_BLOCKS)   // 33554432 table entries

typedef int int4v __attribute__((ext_vector_type(4)));

// Kernel 1: copy the full block table (vectorized 16B) + num_blocks row into d_out.
__global__ void bt_copy_kernel(const int* __restrict__ bt_in,
                               const int* __restrict__ nb_in,
                               int* __restrict__ out) {
    const int4v* __restrict__ src = reinterpret_cast<const int4v*>(bt_in);
    int4v* __restrict__ dst = reinterpret_cast<int4v*>(out);
    const int n4 = NBT / 4;                          // 8388608
    const int stride = gridDim.x * blockDim.x;
    int gid = blockIdx.x * blockDim.x + threadIdx.x;
    for (int i = gid; i < n4; i += stride) {
        dst[i] = src[i];
    }
    // append num_blocks pass-through (scatter kernel overrides touched rows later)
    if (gid < MAX_REQS) {
        out[NBT + gid] = nb_in[gid];
    }
}

// Kernel 2: one block (64 threads) per request: append new block ids + set num_blocks.
__global__ void bt_scatter_kernel(const int* __restrict__ req_indices,
                                  const int* __restrict__ cu,          // [num_reqs+1]
                                  const int* __restrict__ new_ids,     // [total]
                                  const int* __restrict__ overwrite,   // read as int32 (see note)
                                  const int* __restrict__ strides,     // [G]
                                  const int* __restrict__ nb_in,       // [MAX_REQS]
                                  int* __restrict__ out,
                                  int num_reqs) {
    const int r = blockIdx.x;
    if (r >= num_reqs) return;
    const int start = cu[r];
    const int count = cu[r + 1] - start;
    const int row = req_indices[r];
    const int ow = overwrite[r];
    const int dst0 = ow ? 0 : nb_in[row];
    const long long base = (long long)row * (long long)strides[0];
    for (int j = threadIdx.x; j < count; j += blockDim.x) {
        out[base + dst0 + j] = new_ids[start + j];
    }
    if (threadIdx.x == 0) {
        out[NBT + row] = dst0 + count;
    }
}

extern "C" void kernel_launch(void* const* d_in, const int* in_sizes, int n_in,
                              void* d_out, int out_size, void* d_ws, size_t ws_size,
                              hipStream_t stream) {
    // setup_inputs order:
    // 0 req_indices        int32 [num_reqs]
    // 1 cu_num_new_blocks  int32 [G=1, num_reqs+1]
    // 2 new_block_ids      int32 [G, total]
    // 3 overwrite          bool  [num_reqs]  -- interpreted as int32 here (harness int cast)
    // 4 block_table_strides int32 [G]
    // 5 block_table_ptrs   int32 [G]  (unused)
    // 6 num_blocks         int32 [G, MAX_REQS]
    // 7 block_tables       int32 [MAX_REQS, MAX_BLOCKS]
    const int* req_indices = (const int*)d_in[0];
    const int* cu          = (const int*)d_in[1];
    const int* new_ids     = (const int*)d_in[2];
    const int* overwrite   = (const int*)d_in[3];
    const int* strides     = (const int*)d_in[4];
    const int* nb_in       = (const int*)d_in[6];
    const int* bt_in       = (const int*)d_in[7];
    int* out = (int*)d_out;

    const int num_reqs = in_sizes[0];

    // Copy: 2048 blocks x 256 threads, 16B vector grid-stride over 128 MB.
    bt_copy_kernel<<<2048, 256, 0, stream>>>(bt_in, nb_in, out);
    // Scatter: one 64-thread block per request (count == 64 here).
    bt_scatter_kernel<<<num_reqs, 64, 0, stream>>>(req_indices, cu, new_ids, overwrite,
                                                   strides, nb_in, out, num_reqs);
}